// Round 2
// 157.472 us; speedup vs baseline: 1.0361x; 1.0361x over previous
//
#include <hip/hip_runtime.h>

// SmallRNN: B=4096 chains, T=2048 steps, I=1, H=8, O=1, fp32.
// h_t = tanh(x_t*w_ih + W_hh h_{t-1} + b);  out = fc_w . h_T + fc_b
//
// Round 4 (re-run; previous bench was an infra failure, no counters).
// Column-split replicas ("scheme B").
// The two 8-lane replicas previously computed IDENTICAL 8-term dots.
// Now replica h holds the ROTATED state r[rho], rho = j ^ 4h, and each
// lane computes TWO 4-term partials over columns rho^{0..3}:
//   P1: own row rho (seeded with xwb),  P2: partner row rho^4.
// quad_perm XOR1/2/3 (depth-1, quad-local) are the only state gathers;
// one row_ror:8 DPP (= XOR8 within the 16-lane row; +-8 mod 16 is XOR8
// either direction) swaps P2 with the partner, one add completes s.
// Post-activation each lane holds r[rho] directly -> no state fixup.
// 21 -> 17 VALU per step; DPP depth 2 -> 1.
//
// Layout: 16 lanes per chain (8 rows x 2 column-split replicas).
// 256 thr/block = 16 chains, grid 256 -> 1024 waves = 1 wave/SIMD on
// all 256 CUs. Latency/issue-bound by design.

#define B_TOTAL 4096
#define T_STEPS 2048
#define H 8

template <int CTRL>
__device__ __forceinline__ float dppf(float v) {
    int i = __float_as_int(v);
    i = __builtin_amdgcn_mov_dpp(i, CTRL, 0xF, 0xF, true);
    return __int_as_float(i);
}

__global__ __launch_bounds__(256, 1) void rnn_fused(
    const float* __restrict__ x,      // [4096, 2048]
    const float* __restrict__ w_ih,   // [8,1]
    const float* __restrict__ w_hh,   // [8,8]
    const float* __restrict__ b_ih,   // [8]
    const float* __restrict__ b_hh,   // [8]
    const float* __restrict__ fc_w,   // [1,8]
    const float* __restrict__ fc_b,   // [1]
    float* __restrict__ out)          // [4096,1]
{
    const int tid      = threadIdx.x;
    const int p        = tid & 15;          // position within 16-lane row
    const int j        = p & 7;             // hidden index within replica
    const int rho      = j ^ ((p >> 3) << 2); // rotated row: j ^ 4 for high replica
    const int chain    = (blockIdx.x << 4) + (tid >> 4);
    const int baseLane = tid & 48;          // wave-relative base of this row

    // C = 2*log2(e): exp(2*pre) = exp2(C*pre).
    const float C = 2.885390081777927f;

    // r-state weights (r = 1/(1+exp2(C*pre)), h = 1-2r folded into W,b):
    //   W'[row][col] = -2*C*W[row][col]
    //   bP_row = C*(b_row + rowsum(W[row])),  wihC_row = C*wih_row
    // Lane p covers columns rho^{0..3}:
    //   wA[k] = W'[rho  ][rho^k]   (own row,    seeded with xwb)
    //   wB[k] = W'[rho^4][rho^k]   (partner row, exchanged via ror:8)
    float wA[4], wB[4];
    float rowsum = 0.0f;
#pragma unroll
    for (int i = 0; i < H; ++i) rowsum += w_hh[rho * H + i];
#pragma unroll
    for (int k = 0; k < 4; ++k) {
        wA[k] = -2.0f * C * w_hh[rho * H + (rho ^ k)];
        wB[k] = -2.0f * C * w_hh[(rho ^ 4) * H + (rho ^ k)];
    }
    const float wihC = C * w_ih[rho];
    const float bP   = C * (b_ih[rho] + b_hh[rho] + rowsum);

    const float* xp = x + (size_t)chain * T_STEPS;

    float r = 0.5f;   // h = 1 - 2r = 0 for every row

    // One RNN step: 3 quad_perm gathers (depth 1), two 4-term partial
    // chains, one ror:8 exchange, one add, then exp2 + add + rcp.
#define STEP(xval)                                          \
    {                                                       \
        float xwb = fmaf((xval), wihC, bP);  /* off-path */ \
        float g1 = dppf<0xB1>(r);    /* r[rho^1] */         \
        float g2 = dppf<0x4E>(r);    /* r[rho^2] */         \
        float g3 = dppf<0x1B>(r);    /* r[rho^3] */         \
        float p2 = wB[0] * r;                               \
        float p1 = fmaf(wA[0], r, xwb);                     \
        p2 = fmaf(wB[1], g1, p2);                           \
        p1 = fmaf(wA[1], g1, p1);                           \
        p2 = fmaf(wB[2], g2, p2);                           \
        p1 = fmaf(wA[2], g2, p1);                           \
        p2 = fmaf(wB[3], g3, p2);                           \
        p1 = fmaf(wA[3], g3, p1);                           \
        float p2x = dppf<0x128>(p2); /* partner's P2 (XOR8) */ \
        float s = p1 + p2x;                                 \
        float e = __builtin_amdgcn_exp2f(s);                \
        r = __builtin_amdgcn_rcpf(1.0f + e);                \
    }

    // 16-step unroll; prefetch the next 16 x-values a full group ahead.
    float4 c0 = *(const float4*)(xp + 0);
    float4 c1v = *(const float4*)(xp + 4);
    float4 c2v = *(const float4*)(xp + 8);
    float4 c3v = *(const float4*)(xp + 12);

    for (int t = 0; t < T_STEPS; t += 16) {
        float4 n0 = c0, n1 = c1v, n2 = c2v, n3 = c3v;
        if (t + 16 < T_STEPS) {
            n0 = *(const float4*)(xp + t + 16);
            n1 = *(const float4*)(xp + t + 20);
            n2 = *(const float4*)(xp + t + 24);
            n3 = *(const float4*)(xp + t + 28);
        }
        STEP(c0.x) STEP(c0.y) STEP(c0.z) STEP(c0.w)
        STEP(c1v.x) STEP(c1v.y) STEP(c1v.z) STEP(c1v.w)
        STEP(c2v.x) STEP(c2v.y) STEP(c2v.z) STEP(c2v.w)
        STEP(c3v.x) STEP(c3v.y) STEP(c3v.z) STEP(c3v.w)
        c0 = n0; c1v = n1; c2v = n2; c3v = n3;
    }
#undef STEP

    // Final h from r-state; lanes p=0..7 hold rows rho=0..7 (low replica).
    float h = fmaf(-2.0f, r, 1.0f);
    float g[H];
#pragma unroll
    for (int k = 0; k < H; ++k) g[k] = __shfl(h, baseLane + k);
    if (p == 0) {
        float o = fc_b[0];
#pragma unroll
        for (int k = 0; k < H; ++k) o = fmaf(fc_w[k], g[k], o);
        out[chain] = o;
    }
}

extern "C" void kernel_launch(void* const* d_in, const int* in_sizes, int n_in,
                              void* d_out, int out_size, void* d_ws, size_t ws_size,
                              hipStream_t stream) {
    const float* x    = (const float*)d_in[0];
    const float* w_ih = (const float*)d_in[1];
    const float* w_hh = (const float*)d_in[2];
    const float* b_ih = (const float*)d_in[3];
    const float* b_hh = (const float*)d_in[4];
    const float* fc_w = (const float*)d_in[5];
    const float* fc_b = (const float*)d_in[6];
    float* out = (float*)d_out;

    dim3 grid(B_TOTAL / 16);   // 256 blocks -> 1 per CU
    dim3 block(256);           // 4 waves -> 1 per SIMD
    hipLaunchKernelGGL(rnn_fused, grid, block, 0, stream,
                       x, w_ih, w_hh, b_ih, b_hh, fc_w, fc_b, out);
}